// Round 5
// baseline (696.787 us; speedup 1.0000x reference)
//
#include <hip/hip_runtime.h>

typedef __bf16 bf16x8 __attribute__((ext_vector_type(8)));
typedef __bf16 bf16x4 __attribute__((ext_vector_type(4)));
typedef float  f32x4  __attribute__((ext_vector_type(4)));

#define GLOAD_LDS16(g, l) \
  __builtin_amdgcn_global_load_lds((const __attribute__((address_space(1))) void*)(g), \
                                   (__attribute__((address_space(3))) void*)(l), 16, 0, 0)

// ---------------------------------------------------------------------------
// Weight transpose + fp32->bf16 convert: W[K=2048][N=2048] -> Wt[N][K]
// ---------------------------------------------------------------------------
__global__ __launch_bounds__(256) void wcvt_kernel(
    const float* __restrict__ W0, const float* __restrict__ W1,
    const float* __restrict__ W2, const float* __restrict__ W3,
    __bf16* __restrict__ WtBase)
{
  const float* W = (blockIdx.z == 0) ? W0 : (blockIdx.z == 1) ? W1 : (blockIdx.z == 2) ? W2 : W3;
  __bf16* dst = WtBase + (size_t)blockIdx.z * 2048 * 2048;
  __shared__ float tile[32][33];
  const int tx = threadIdx.x & 31, ty = threadIdx.x >> 5;  // 32 x 8
  const int gi = blockIdx.x * 32, gj = blockIdx.y * 32;
  #pragma unroll
  for (int r = 0; r < 32; r += 8)
    tile[ty + r][tx] = W[(size_t)(gi + ty + r) * 2048 + gj + tx];
  __syncthreads();
  #pragma unroll
  for (int r = 0; r < 32; r += 8)
    dst[(size_t)(gj + ty + r) * 2048 + gi + tx] = (__bf16)tile[tx][ty + r];
}

// ---------------------------------------------------------------------------
// LayerNorm: x[M][2048] f32 -> xn[M][2048] bf16   (one block per token)
// ---------------------------------------------------------------------------
__global__ __launch_bounds__(256) void ln_kernel(
    const float* __restrict__ x, const float* __restrict__ gw,
    const float* __restrict__ bw, __bf16* __restrict__ xn)
{
  __shared__ float red[8];
  const size_t base = (size_t)blockIdx.x * 2048;
  const int t = threadIdx.x;
  float4 v0 = *(const float4*)(x + base + t * 4);
  float4 v1 = *(const float4*)(x + base + 1024 + t * 4);
  float sm = v0.x + v0.y + v0.z + v0.w + v1.x + v1.y + v1.z + v1.w;
  float sq = v0.x*v0.x + v0.y*v0.y + v0.z*v0.z + v0.w*v0.w
           + v1.x*v1.x + v1.y*v1.y + v1.z*v1.z + v1.w*v1.w;
  #pragma unroll
  for (int off = 32; off; off >>= 1) {
    sm += __shfl_down(sm, off);
    sq += __shfl_down(sq, off);
  }
  if ((t & 63) == 0) { red[t >> 6] = sm; red[4 + (t >> 6)] = sq; }
  __syncthreads();
  const float fs = red[0] + red[1] + red[2] + red[3];
  const float fq = red[4] + red[5] + red[6] + red[7];
  const float mu = fs * (1.f / 2048.f);
  const float var = fq * (1.f / 2048.f) - mu * mu;
  const float rs = rsqrtf(var + 1e-5f);
  float4 g0 = *(const float4*)(gw + t * 4);
  float4 g1 = *(const float4*)(gw + 1024 + t * 4);
  float4 b0 = *(const float4*)(bw + t * 4);
  float4 b1 = *(const float4*)(bw + 1024 + t * 4);
  bf16x4 o0, o1;
  o0[0] = (__bf16)((v0.x - mu) * rs * g0.x + b0.x);
  o0[1] = (__bf16)((v0.y - mu) * rs * g0.y + b0.y);
  o0[2] = (__bf16)((v0.z - mu) * rs * g0.z + b0.z);
  o0[3] = (__bf16)((v0.w - mu) * rs * g0.w + b0.w);
  o1[0] = (__bf16)((v1.x - mu) * rs * g1.x + b1.x);
  o1[1] = (__bf16)((v1.y - mu) * rs * g1.y + b1.y);
  o1[2] = (__bf16)((v1.z - mu) * rs * g1.z + b1.z);
  o1[3] = (__bf16)((v1.w - mu) * rs * g1.w + b1.w);
  *(bf16x4*)(xn + base + t * 4) = o0;
  *(bf16x4*)(xn + base + 1024 + t * 4) = o1;
}

// ---------------------------------------------------------------------------
// 256x256 GEMM, 8 waves (2M x 4N), fine-interleaved 4-deep pipeline:
// BK=32, FOUR 32KB LDS buffers, prefetch distance 3 K-steps. Per K-step:
//   barrier | issue 4 gloads (tile t+3, buf (t+3)&3) | vmcnt(12) | barrier |
//   ds_read 4B+4A frags | setprio 16 MFMA | barrier | ds_read 4A | 16 MFMA
// vmcnt never drains to 0 in the main loop (T3+T4); setprio (T5); LDS layout
// pairs two 64B rows per 128B superrow with seg XOR swizzle (T2):
//   chunk ci: sr=ci>>3, pseg=ci&7, slog=pseg^(sr&7), row=2sr+(slog>>2),
//   kseg=slog&3. gload_lds dest stays lane-linear; ds_read_b128 conflict-free.
// MODE 0: QKV fused (blockIdx.y: which=y>>3, n0=(y&7)*256; bf16 out to qkv)
// MODE 1: O projection (fp32 out + bias to d_out)
// ---------------------------------------------------------------------------
template <int MODE>
__global__ __launch_bounds__(512, 2) void gemm256(
    const __bf16* __restrict__ A, int lda,
    const __bf16* __restrict__ WtBase,
    const float* __restrict__ b0, const float* __restrict__ b1,
    const float* __restrict__ b2, void* __restrict__ outp)
{
  __shared__ __attribute__((aligned(16))) char smem[131072];  // 4 bufs x (A16K|B16K)
  const int tid = threadIdx.x, lane = tid & 63, wid = tid >> 6;
  const int wm = wid >> 2, wn = wid & 3;
  const int m0 = blockIdx.x * 256;
  int which, n0;
  const __bf16* Bt;
  const float* bias;
  if (MODE == 0) {
    which = blockIdx.y >> 3;
    n0 = (blockIdx.y & 7) * 256;
    Bt = WtBase + (size_t)which * 2048 * 2048 + (size_t)n0 * 2048;
    bias = (which == 0) ? b0 : (which == 1) ? b1 : b2;
  } else {
    which = 0;
    n0 = blockIdx.y * 256;
    Bt = WtBase + (size_t)n0 * 2048;
    bias = b0;
  }

  // ---- staging: thread handles chunks ci0=tid, ci1=512+tid per operand ----
  const int ci0 = tid, ci1 = 512 + tid;
  const int sr0 = ci0 >> 3, sg0 = (ci0 & 7) ^ (sr0 & 7);
  const int sr1 = ci1 >> 3, sg1 = (ci1 & 7) ^ (sr1 & 7);
  const int r0 = sr0 * 2 + (sg0 >> 2), c0 = (sg0 & 3) * 8;
  const int r1 = sr1 * 2 + (sg1 >> 2), c1 = (sg1 & 3) * 8;
  const __bf16* Ag0 = A + (size_t)(m0 + r0) * lda + c0;
  const __bf16* Ag1 = A + (size_t)(m0 + r1) * lda + c1;
  const __bf16* Bg0 = Bt + (size_t)r0 * 2048 + c0;
  const __bf16* Bg1 = Bt + (size_t)r1 * 2048 + c1;
  const int ldst = __builtin_amdgcn_readfirstlane(wid * 1024);

#define STAGE(buf, kt)                                                        \
  do {                                                                        \
    const int ko_ = (kt) * 32;                                                \
    GLOAD_LDS16(Ag0 + ko_, smem + (buf) * 32768 + ldst);                      \
    GLOAD_LDS16(Ag1 + ko_, smem + (buf) * 32768 + 8192 + ldst);               \
    GLOAD_LDS16(Bg0 + ko_, smem + (buf) * 32768 + 16384 + ldst);              \
    GLOAD_LDS16(Bg1 + ko_, smem + (buf) * 32768 + 16384 + 8192 + ldst);       \
  } while (0)

  // ---- fragment read bases (swizzle XOR invariant across mi/ni) ----
  const int fr = lane & 15, sl = lane >> 4;
  const int slogf = sl | ((fr & 1) << 2);
  const int rbA = wm * 128 + fr, rbB = wn * 64 + fr;
  const int abase = (rbA >> 1) * 128 + ((slogf ^ ((rbA >> 1) & 7)) * 16);
  const int bbase = (rbB >> 1) * 128 + ((slogf ^ ((rbB >> 1) & 7)) * 16);

  f32x4 acc[8][4];
  #pragma unroll
  for (int i = 0; i < 8; i++)
    #pragma unroll
    for (int j = 0; j < 4; j++) acc[i][j] = (f32x4){0.f, 0.f, 0.f, 0.f};

  STAGE(0, 0);
  STAGE(1, 1);
  STAGE(2, 2);
  const int NT = 2048 / 32;  // 64

  for (int t = 0; t < NT; t++) {
    const int br = t & 3;
    __builtin_amdgcn_s_barrier();  // close step t-1 reads of buf (t+3)&3
    if (t + 3 < NT) {
      STAGE((t + 3) & 3, t + 3);   // 4 loads, 3 steps ahead
      asm volatile("s_waitcnt vmcnt(12)" ::: "memory");  // tile-t landed (own)
    } else {
      asm volatile("s_waitcnt vmcnt(0)" ::: "memory");   // tail only
    }
    __builtin_amdgcn_s_barrier();  // tile-t visible to all waves
    const char* Ab = smem + br * 32768;
    const char* Bb = Ab + 16384;
    bf16x8 bfr[4], afr[4];
    #pragma unroll
    for (int ni = 0; ni < 4; ni++)
      bfr[ni] = *(const bf16x8*)(Bb + bbase + ni * 1024);
    #pragma unroll
    for (int i = 0; i < 4; i++)
      afr[i] = *(const bf16x8*)(Ab + abase + i * 1024);
    __builtin_amdgcn_s_setprio(1);
    #pragma unroll
    for (int i = 0; i < 4; i++)
      #pragma unroll
      for (int ni = 0; ni < 4; ni++)
        acc[i][ni] = __builtin_amdgcn_mfma_f32_16x16x32_bf16(afr[i], bfr[ni], acc[i][ni], 0, 0, 0);
    __builtin_amdgcn_s_setprio(0);
    __builtin_amdgcn_s_barrier();  // phase lockstep
    #pragma unroll
    for (int i = 0; i < 4; i++)
      afr[i] = *(const bf16x8*)(Ab + abase + 4096 + i * 1024);
    __builtin_amdgcn_s_setprio(1);
    #pragma unroll
    for (int i = 0; i < 4; i++)
      #pragma unroll
      for (int ni = 0; ni < 4; ni++)
        acc[4 + i][ni] = __builtin_amdgcn_mfma_f32_16x16x32_bf16(afr[i], bfr[ni], acc[4 + i][ni], 0, 0, 0);
    __builtin_amdgcn_s_setprio(0);
  }
#undef STAGE

  // epilogue: C/D layout col=lane&15, row=(lane>>4)*4+j  [m89-verified]
  const int colf = lane & 15, rowf = (lane >> 4) * 4;
  #pragma unroll
  for (int mi = 0; mi < 8; mi++) {
    const int rw = m0 + wm * 128 + mi * 16 + rowf;
    #pragma unroll
    for (int ni = 0; ni < 4; ni++) {
      const int cc = n0 + wn * 64 + ni * 16 + colf;
      const float bi = bias[cc];
      if (MODE == 0) {
        __bf16* qkv = (__bf16*)outp;
        #pragma unroll
        for (int j = 0; j < 4; j++)
          qkv[(size_t)(rw + j) * 6144 + (size_t)which * 2048 + cc] =
              (__bf16)(acc[mi][ni][j] + bi);
      } else {
        float* out = (float*)outp;
        #pragma unroll
        for (int j = 0; j < 4; j++)
          out[(size_t)(rw + j) * 2048 + cc] = acc[mi][ni][j] + bi;
      }
    }
  }
}

// ---------------------------------------------------------------------------
// Per-token attention: scores[16][16] = q@k^T/sqrt(2048), softmax rows,
// ctx[16][128] = P@v. One wave per token, 4 tokens/block. ctx overwrites the
// q-slot of qkv in place (safe: wave reads its token fully into LDS first).
// ---------------------------------------------------------------------------
__global__ __launch_bounds__(256) void attn_kernel(__bf16* __restrict__ qkv)
{
  __shared__ __bf16 att[4 * 6144];   // 48 KB
  __shared__ float Psh[4 * 256];     // 4 KB
  const int tid = threadIdx.x, lane = tid & 63, w = tid >> 6;
  const size_t token = (size_t)blockIdx.x * 4 + w;
  const __bf16* src = qkv + token * 6144;
  char* ldsb = (char*)att;
  const int lbase = __builtin_amdgcn_readfirstlane(w * 12288);
  #pragma unroll
  for (int r = 0; r < 12; r++)
    GLOAD_LDS16(src + r * 512 + lane * 8, ldsb + lbase + r * 1024);
  __syncthreads();

  const __bf16* my = att + w * 6144;
  // QK^T: lane handles h = lane>>2, g in {gq*4 .. gq*4+3}
  const int h = lane >> 2, gq = lane & 3;
  const __bf16* qrow = my + h * 128;
  float s[4] = {0.f, 0.f, 0.f, 0.f};
  for (int d = 0; d < 128; d += 8) {
    bf16x8 qv = *(const bf16x8*)(qrow + d);
    float qf[8];
    #pragma unroll
    for (int j = 0; j < 8; j++) qf[j] = (float)qv[j];
    #pragma unroll
    for (int i = 0; i < 4; i++) {
      bf16x8 kv = *(const bf16x8*)(my + 2048 + (gq * 4 + i) * 128 + d);
      #pragma unroll
      for (int j = 0; j < 8; j++) s[i] += qf[j] * (float)kv[j];
    }
  }
  const float scale = 0.022097086912079612f;  // 1/sqrt(2048)
  #pragma unroll
  for (int i = 0; i < 4; i++) s[i] *= scale;
  float mx = fmaxf(fmaxf(s[0], s[1]), fmaxf(s[2], s[3]));
  mx = fmaxf(mx, __shfl_xor(mx, 1));
  mx = fmaxf(mx, __shfl_xor(mx, 2));
  float p[4], sum = 0.f;
  #pragma unroll
  for (int i = 0; i < 4; i++) { p[i] = __expf(s[i] - mx); sum += p[i]; }
  sum += __shfl_xor(sum, 1);
  sum += __shfl_xor(sum, 2);
  const float inv = 1.f / sum;
  #pragma unroll
  for (int i = 0; i < 4; i++) Psh[w * 256 + h * 16 + gq * 4 + i] = p[i] * inv;
  __syncthreads();

  // PV: lane computes ctx[h2][db..db+31]
  const int h2 = lane >> 2, db = (lane & 3) * 32;
  const __bf16* vb = my + 4096;
  float acc[32];
  #pragma unroll
  for (int i = 0; i < 32; i++) acc[i] = 0.f;
  for (int g = 0; g < 16; g++) {
    const float pv = Psh[w * 256 + h2 * 16 + g];
    #pragma unroll
    for (int c = 0; c < 4; c++) {
      bf16x8 vv = *(const bf16x8*)(vb + g * 128 + db + c * 8);
      #pragma unroll
      for (int j = 0; j < 8; j++) acc[c * 8 + j] += pv * (float)vv[j];
    }
  }
  __bf16* dst = qkv + token * 6144 + h2 * 128 + db;
  #pragma unroll
  for (int c = 0; c < 4; c++) {
    bf16x8 ov;
    #pragma unroll
    for (int j = 0; j < 8; j++) ov[j] = (__bf16)acc[c * 8 + j];
    *(bf16x8*)(dst + c * 8) = ov;
  }
}

// ---------------------------------------------------------------------------
extern "C" void kernel_launch(void* const* d_in, const int* in_sizes, int n_in,
                              void* d_out, int out_size, void* d_ws, size_t ws_size,
                              hipStream_t stream)
{
  const float* x    = (const float*)d_in[0];
  const float* ln_g = (const float*)d_in[1];
  const float* ln_b = (const float*)d_in[2];
  const float* Wq   = (const float*)d_in[3];
  const float* bq   = (const float*)d_in[4];
  const float* Wk   = (const float*)d_in[5];
  const float* bk   = (const float*)d_in[6];
  const float* Wv   = (const float*)d_in[7];
  const float* bv   = (const float*)d_in[8];
  const float* Wo   = (const float*)d_in[9];
  const float* bo   = (const float*)d_in[10];
  float* out = (float*)d_out;
  const int M = in_sizes[0] / 2048;  // 16384

  // Workspace (224 MB): Wt 32 MB | qkv 192 MB. xn (64 MB bf16) lives in d_out
  // (128 MB fp32): consumed by QKV GEMM; d_out only written by final O-GEMM.
  char* ws = (char*)d_ws;
  __bf16* Wt  = (__bf16*)ws;
  __bf16* qkv = (__bf16*)(ws + 33554432);
  __bf16* xn  = (__bf16*)d_out;

  wcvt_kernel<<<dim3(64, 64, 4), 256, 0, stream>>>(Wq, Wk, Wv, Wo, Wt);
  ln_kernel<<<M, 256, 0, stream>>>(x, ln_g, ln_b, xn);
  gemm256<0><<<dim3(M / 256, 24), 512, 0, stream>>>(xn, 2048, Wt, bq, bk, bv, (void*)qkv);
  attn_kernel<<<M / 4, 256, 0, stream>>>(qkv);
  gemm256<1><<<dim3(M / 256, 8), 512, 0, stream>>>(qkv, 6144, Wt + (size_t)3 * 2048 * 2048,
                                                   bo, nullptr, nullptr, (void*)out);
}

// Round 6
// 624.240 us; speedup vs baseline: 1.1162x; 1.1162x over previous
//
#include <hip/hip_runtime.h>

typedef __bf16 bf16x8 __attribute__((ext_vector_type(8)));
typedef __bf16 bf16x4 __attribute__((ext_vector_type(4)));
typedef float  f32x4  __attribute__((ext_vector_type(4)));

#define GLOAD_LDS16(g, l) \
  __builtin_amdgcn_global_load_lds((const __attribute__((address_space(1))) void*)(g), \
                                   (__attribute__((address_space(3))) void*)(l), 16, 0, 0)

// ---------------------------------------------------------------------------
// Weight transpose + fp32->bf16 convert: W[K=2048][N=2048] -> Wt[N][K]
// ---------------------------------------------------------------------------
__global__ __launch_bounds__(256) void wcvt_kernel(
    const float* __restrict__ W0, const float* __restrict__ W1,
    const float* __restrict__ W2, const float* __restrict__ W3,
    __bf16* __restrict__ WtBase)
{
  const float* W = (blockIdx.z == 0) ? W0 : (blockIdx.z == 1) ? W1 : (blockIdx.z == 2) ? W2 : W3;
  __bf16* dst = WtBase + (size_t)blockIdx.z * 2048 * 2048;
  __shared__ float tile[32][33];
  const int tx = threadIdx.x & 31, ty = threadIdx.x >> 5;  // 32 x 8
  const int gi = blockIdx.x * 32, gj = blockIdx.y * 32;
  #pragma unroll
  for (int r = 0; r < 32; r += 8)
    tile[ty + r][tx] = W[(size_t)(gi + ty + r) * 2048 + gj + tx];
  __syncthreads();
  #pragma unroll
  for (int r = 0; r < 32; r += 8)
    dst[(size_t)(gj + ty + r) * 2048 + gi + tx] = (__bf16)tile[tx][ty + r];
}

// ---------------------------------------------------------------------------
// LayerNorm: x[M][2048] f32 -> xn[M][2048] bf16   (one block per token)
// ---------------------------------------------------------------------------
__global__ __launch_bounds__(256) void ln_kernel(
    const float* __restrict__ x, const float* __restrict__ gw,
    const float* __restrict__ bw, __bf16* __restrict__ xn)
{
  __shared__ float red[8];
  const size_t base = (size_t)blockIdx.x * 2048;
  const int t = threadIdx.x;
  float4 v0 = *(const float4*)(x + base + t * 4);
  float4 v1 = *(const float4*)(x + base + 1024 + t * 4);
  float sm = v0.x + v0.y + v0.z + v0.w + v1.x + v1.y + v1.z + v1.w;
  float sq = v0.x*v0.x + v0.y*v0.y + v0.z*v0.z + v0.w*v0.w
           + v1.x*v1.x + v1.y*v1.y + v1.z*v1.z + v1.w*v1.w;
  #pragma unroll
  for (int off = 32; off; off >>= 1) {
    sm += __shfl_down(sm, off);
    sq += __shfl_down(sq, off);
  }
  if ((t & 63) == 0) { red[t >> 6] = sm; red[4 + (t >> 6)] = sq; }
  __syncthreads();
  const float fs = red[0] + red[1] + red[2] + red[3];
  const float fq = red[4] + red[5] + red[6] + red[7];
  const float mu = fs * (1.f / 2048.f);
  const float var = fq * (1.f / 2048.f) - mu * mu;
  const float rs = rsqrtf(var + 1e-5f);
  float4 g0 = *(const float4*)(gw + t * 4);
  float4 g1 = *(const float4*)(gw + 1024 + t * 4);
  float4 b0 = *(const float4*)(bw + t * 4);
  float4 b1 = *(const float4*)(bw + 1024 + t * 4);
  bf16x4 o0, o1;
  o0[0] = (__bf16)((v0.x - mu) * rs * g0.x + b0.x);
  o0[1] = (__bf16)((v0.y - mu) * rs * g0.y + b0.y);
  o0[2] = (__bf16)((v0.z - mu) * rs * g0.z + b0.z);
  o0[3] = (__bf16)((v0.w - mu) * rs * g0.w + b0.w);
  o1[0] = (__bf16)((v1.x - mu) * rs * g1.x + b1.x);
  o1[1] = (__bf16)((v1.y - mu) * rs * g1.y + b1.y);
  o1[2] = (__bf16)((v1.z - mu) * rs * g1.z + b1.z);
  o1[3] = (__bf16)((v1.w - mu) * rs * g1.w + b1.w);
  *(bf16x4*)(xn + base + t * 4) = o0;
  *(bf16x4*)(xn + base + 1024 + t * 4) = o1;
}

// ---------------------------------------------------------------------------
// 256x256 GEMM, 8 waves (2M x 4N), BK=64, 4 phases per K-tile (m201-style
// fine interleave). LDS 128 KB = 2 dbuf x {A-half0,A-half1,B-half0,B-half1}
// of 16 KB each. A-half h = tile rows with bit6==h (what phase mh=h reads);
// B-half h = tile N-rows with bit5==h (phase nh=h). Swizzle: within a half,
// row la (128B), phys_seg = log_seg ^ (la&7) (measured conflict-free).
// Phase = { vmcnt(6); ds_read frag-set; stage one half (2 gload_lds);
//           barrier; lgkmcnt(0)+sched_barrier; setprio1; 16 MFMA; setprio0;
//           barrier }.
// Phase order (mh,nh): (0,0),(0,1),(1,1),(1,0) — B frags register-cached.
// Stage slots: phi0: A1(kt+1); phi1: A0(kt+2); phi2: B0(kt+2); phi3: B1(kt+2).
// Stage->consume distance >= 6 phases; vmcnt(6) = 3-half lag covers all.
// MODE 0: QKV fused (blockIdx.y: which=y>>3, n0=(y&7)*256; bf16 out to qkv)
// MODE 1: O projection (fp32 out + bias to d_out)
// ---------------------------------------------------------------------------
template <int MODE>
__global__ __launch_bounds__(512, 2) void gemm256(
    const __bf16* __restrict__ A, int lda,
    const __bf16* __restrict__ WtBase,
    const float* __restrict__ b0, const float* __restrict__ b1,
    const float* __restrict__ b2, void* __restrict__ outp)
{
  __shared__ __attribute__((aligned(16))) char smem[131072];
  const int tid = threadIdx.x, lane = tid & 63, wid = tid >> 6;
  const int wm = wid >> 2, wn = wid & 3;
  const int m0 = blockIdx.x * 256;
  int which, n0;
  const __bf16* Bt;
  const float* bias;
  if (MODE == 0) {
    which = blockIdx.y >> 3;
    n0 = (blockIdx.y & 7) * 256;
    Bt = WtBase + (size_t)which * 2048 * 2048 + (size_t)n0 * 2048;
    bias = (which == 0) ? b0 : (which == 1) ? b1 : b2;
  } else {
    which = 0;
    n0 = blockIdx.y * 256;
    Bt = WtBase + (size_t)n0 * 2048;
    bias = b0;
  }

  // ---- staging: thread covers chunk ci0=tid (local row lr0=tid>>3) and
  //      ci1=tid+512 (local row lr0+64) of each 16KB half. Pre-swizzled
  //      global source: log_seg = (tid&7) ^ (lr0&7) (same for both chunks).
  const int lr0 = tid >> 3;
  const int sg  = (tid & 7) ^ (lr0 & 7);
  // A-half h local row lr -> tile row: (lr>>6)*128 + h*64 + (lr&63)
  const __bf16* Ag0 = A + (size_t)(m0 + lr0) * lda + sg * 8;         // h=0,c0
  const __bf16* Ag1 = A + (size_t)(m0 + 64 + lr0) * lda + sg * 8;    // h=1,c0
  // B-half h local row lr -> tile N-row: (lr>>5)*64 + h*32 + (lr&31)
  const __bf16* Bg0 = Bt + (size_t)((lr0 >> 5) * 64 + (lr0 & 31)) * 2048 + sg * 8;
  const __bf16* Bg1 = Bt + (size_t)((lr0 >> 5) * 64 + 32 + (lr0 & 31)) * 2048 + sg * 8;
  const int ldst = __builtin_amdgcn_readfirstlane(wid * 1024);

#define STAGE_A(H, DBB, KT)                                                        \
  do {                                                                             \
    GLOAD_LDS16(Ag##H + (KT) * 64, smem + (DBB) + (H) * 16384 + ldst);             \
    GLOAD_LDS16(Ag##H + (size_t)128 * lda + (KT) * 64,                             \
                smem + (DBB) + (H) * 16384 + 8192 + ldst);                         \
  } while (0)
#define STAGE_B(H, DBB, KT)                                                        \
  do {                                                                             \
    GLOAD_LDS16(Bg##H + (KT) * 64, smem + (DBB) + 32768 + (H) * 16384 + ldst);     \
    GLOAD_LDS16(Bg##H + 262144 + (KT) * 64,                                        \
                smem + (DBB) + 32768 + (H) * 16384 + 8192 + ldst);                 \
  } while (0)

  // ---- fragment read offsets within a half (local rows; swizzle XOR) ----
  const int fr = lane & 15, sl = lane >> 4, x7 = fr & 7;
  const int aoff0 = (wm * 64 + fr) * 128 + ((sl) ^ x7) * 16;
  const int aoff1 = (wm * 64 + fr) * 128 + ((4 + sl) ^ x7) * 16;
  const int boff0 = (wn * 32 + fr) * 128 + ((sl) ^ x7) * 16;
  const int boff1 = (wn * 32 + fr) * 128 + ((4 + sl) ^ x7) * 16;

  bf16x8 afr[4][2], bfr0[2][2], bfr1[2][2];
  f32x4 acc[8][4];
  #pragma unroll
  for (int i = 0; i < 8; i++)
    #pragma unroll
    for (int j = 0; j < 4; j++) acc[i][j] = (f32x4){0.f, 0.f, 0.f, 0.f};

#define READ_A(MH, DB)                                                             \
  _Pragma("unroll") for (int mi = 0; mi < 4; mi++)                                 \
  _Pragma("unroll") for (int kk = 0; kk < 2; kk++)                                 \
    afr[mi][kk] = *(const bf16x8*)(smem + (DB) + (MH) * 16384 +                    \
                                   (kk ? aoff1 : aoff0) + mi * 2048);
#define READ_B(NH, DB, DEST)                                                       \
  _Pragma("unroll") for (int ni = 0; ni < 2; ni++)                                 \
  _Pragma("unroll") for (int kk = 0; kk < 2; kk++)                                 \
    DEST[ni][kk] = *(const bf16x8*)(smem + (DB) + 32768 + (NH) * 16384 +           \
                                    (kk ? boff1 : boff0) + ni * 2048);
#define MFMA16(MH, NH, BSET)                                                       \
  _Pragma("unroll") for (int kk = 0; kk < 2; kk++)                                 \
  _Pragma("unroll") for (int mi = 0; mi < 4; mi++)                                 \
  _Pragma("unroll") for (int ni = 0; ni < 2; ni++)                                 \
    acc[(MH) * 4 + mi][(NH) * 2 + ni] = __builtin_amdgcn_mfma_f32_16x16x32_bf16(   \
        afr[mi][kk], BSET[ni][kk], acc[(MH) * 4 + mi][(NH) * 2 + ni], 0, 0, 0);
#define PHASE_TAIL(MH, NH, BSET)                                                   \
  __builtin_amdgcn_s_barrier();                                                    \
  asm volatile("s_waitcnt lgkmcnt(0)" ::: "memory");                               \
  __builtin_amdgcn_sched_barrier(0);                                               \
  __builtin_amdgcn_s_setprio(1);                                                   \
  MFMA16(MH, NH, BSET);                                                            \
  __builtin_amdgcn_s_setprio(0);                                                   \
  __builtin_amdgcn_s_barrier();

  // ---- prologue: kt0 {A0,B0,A1,B1} + kt1 {A0,B0,B1}; full drain once ----
  STAGE_A(0, 0, 0);
  STAGE_B(0, 0, 0);
  STAGE_A(1, 0, 0);
  STAGE_B(1, 0, 0);
  STAGE_A(0, 65536, 1);
  STAGE_B(0, 65536, 1);
  STAGE_B(1, 65536, 1);
  __syncthreads();

  const int NT = 32;  // 2048 / 64
  for (int kt = 0; kt < NT; kt++) {
    const int db  = (kt & 1) << 16;
    const int dbn = db ^ 65536;
    // ---- phase 0: (mh0, nh0) ----
    if (kt == NT - 1) { asm volatile("s_waitcnt vmcnt(0)" ::: "memory"); }
    else              { asm volatile("s_waitcnt vmcnt(6)" ::: "memory"); }
    READ_A(0, db);
    READ_B(0, db, bfr0);
    if (kt + 1 < NT) STAGE_A(1, dbn, kt + 1);
    PHASE_TAIL(0, 0, bfr0);
    // ---- phase 1: (mh0, nh1) ----
    asm volatile("s_waitcnt vmcnt(6)" ::: "memory");
    READ_B(1, db, bfr1);
    if (kt + 2 < NT) STAGE_A(0, db, kt + 2);
    PHASE_TAIL(0, 1, bfr1);
    // ---- phase 2: (mh1, nh1) ----
    asm volatile("s_waitcnt vmcnt(6)" ::: "memory");
    READ_A(1, db);
    if (kt + 2 < NT) STAGE_B(0, db, kt + 2);
    PHASE_TAIL(1, 1, bfr1);
    // ---- phase 3: (mh1, nh0) — no ds_reads (A,B frags cached) ----
    if (kt + 2 < NT) STAGE_B(1, db, kt + 2);
    PHASE_TAIL(1, 0, bfr0);
  }
#undef STAGE_A
#undef STAGE_B
#undef READ_A
#undef READ_B
#undef MFMA16
#undef PHASE_TAIL

  // epilogue: C/D layout col=lane&15, row=(lane>>4)*4+j  [m89-verified]
  const int colf = lane & 15, rowf = (lane >> 4) * 4;
  #pragma unroll
  for (int mi = 0; mi < 8; mi++) {
    const int rw = m0 + wm * 128 + mi * 16 + rowf;
    #pragma unroll
    for (int ni = 0; ni < 4; ni++) {
      const int cc = n0 + wn * 64 + ni * 16 + colf;
      const float bi = bias[cc];
      if (MODE == 0) {
        __bf16* qkv = (__bf16*)outp;
        #pragma unroll
        for (int j = 0; j < 4; j++)
          qkv[(size_t)(rw + j) * 6144 + (size_t)which * 2048 + cc] =
              (__bf16)(acc[mi][ni][j] + bi);
      } else {
        float* out = (float*)outp;
        #pragma unroll
        for (int j = 0; j < 4; j++)
          out[(size_t)(rw + j) * 2048 + cc] = acc[mi][ni][j] + bi;
      }
    }
  }
}

// ---------------------------------------------------------------------------
// Per-token attention: scores[16][16] = q@k^T/sqrt(2048), softmax rows,
// ctx[16][128] = P@v. One wave per token, 4 tokens/block. ctx overwrites the
// q-slot of qkv in place (safe: wave reads its token fully into LDS first).
// ---------------------------------------------------------------------------
__global__ __launch_bounds__(256) void attn_kernel(__bf16* __restrict__ qkv)
{
  __shared__ __bf16 att[4 * 6144];   // 48 KB
  __shared__ float Psh[4 * 256];     // 4 KB
  const int tid = threadIdx.x, lane = tid & 63, w = tid >> 6;
  const size_t token = (size_t)blockIdx.x * 4 + w;
  const __bf16* src = qkv + token * 6144;
  char* ldsb = (char*)att;
  const int lbase = __builtin_amdgcn_readfirstlane(w * 12288);
  #pragma unroll
  for (int r = 0; r < 12; r++)
    GLOAD_LDS16(src + r * 512 + lane * 8, ldsb + lbase + r * 1024);
  __syncthreads();

  const __bf16* my = att + w * 6144;
  // QK^T: lane handles h = lane>>2, g in {gq*4 .. gq*4+3}
  const int h = lane >> 2, gq = lane & 3;
  const __bf16* qrow = my + h * 128;
  float s[4] = {0.f, 0.f, 0.f, 0.f};
  for (int d = 0; d < 128; d += 8) {
    bf16x8 qv = *(const bf16x8*)(qrow + d);
    float qf[8];
    #pragma unroll
    for (int j = 0; j < 8; j++) qf[j] = (float)qv[j];
    #pragma unroll
    for (int i = 0; i < 4; i++) {
      bf16x8 kv = *(const bf16x8*)(my + 2048 + (gq * 4 + i) * 128 + d);
      #pragma unroll
      for (int j = 0; j < 8; j++) s[i] += qf[j] * (float)kv[j];
    }
  }
  const float scale = 0.022097086912079612f;  // 1/sqrt(2048)
  #pragma unroll
  for (int i = 0; i < 4; i++) s[i] *= scale;
  float mx = fmaxf(fmaxf(s[0], s[1]), fmaxf(s[2], s[3]));
  mx = fmaxf(mx, __shfl_xor(mx, 1));
  mx = fmaxf(mx, __shfl_xor(mx, 2));
  float p[4], sum = 0.f;
  #pragma unroll
  for (int i = 0; i < 4; i++) { p[i] = __expf(s[i] - mx); sum += p[i]; }
  sum += __shfl_xor(sum, 1);
  sum += __shfl_xor(sum, 2);
  const float inv = 1.f / sum;
  #pragma unroll
  for (int i = 0; i < 4; i++) Psh[w * 256 + h * 16 + gq * 4 + i] = p[i] * inv;
  __syncthreads();

  // PV: lane computes ctx[h2][db..db+31]
  const int h2 = lane >> 2, db = (lane & 3) * 32;
  const __bf16* vb = my + 4096;
  float acc[32];
  #pragma unroll
  for (int i = 0; i < 32; i++) acc[i] = 0.f;
  for (int g = 0; g < 16; g++) {
    const float pv = Psh[w * 256 + h2 * 16 + g];
    #pragma unroll
    for (int c = 0; c < 4; c++) {
      bf16x8 vv = *(const bf16x8*)(vb + g * 128 + db + c * 8);
      #pragma unroll
      for (int j = 0; j < 8; j++) acc[c * 8 + j] += pv * (float)vv[j];
    }
  }
  __bf16* dst = qkv + token * 6144 + h2 * 128 + db;
  #pragma unroll
  for (int c = 0; c < 4; c++) {
    bf16x8 ov;
    #pragma unroll
    for (int j = 0; j < 8; j++) ov[j] = (__bf16)acc[c * 8 + j];
    *(bf16x8*)(dst + c * 8) = ov;
  }
}

// ---------------------------------------------------------------------------
extern "C" void kernel_launch(void* const* d_in, const int* in_sizes, int n_in,
                              void* d_out, int out_size, void* d_ws, size_t ws_size,
                              hipStream_t stream)
{
  const float* x    = (const float*)d_in[0];
  const float* ln_g = (const float*)d_in[1];
  const float* ln_b = (const float*)d_in[2];
  const float* Wq   = (const float*)d_in[3];
  const float* bq   = (const float*)d_in[4];
  const float* Wk   = (const float*)d_in[5];
  const float* bk   = (const float*)d_in[6];
  const float* Wv   = (const float*)d_in[7];
  const float* bv   = (const float*)d_in[8];
  const float* Wo   = (const float*)d_in[9];
  const float* bo   = (const float*)d_in[10];
  float* out = (float*)d_out;
  const int M = in_sizes[0] / 2048;  // 16384

  // Workspace (224 MB): Wt 32 MB | qkv 192 MB. xn (64 MB bf16) lives in d_out
  // (128 MB fp32): consumed by QKV GEMM; d_out only written by final O-GEMM.
  char* ws = (char*)d_ws;
  __bf16* Wt  = (__bf16*)ws;
  __bf16* qkv = (__bf16*)(ws + 33554432);
  __bf16* xn  = (__bf16*)d_out;

  wcvt_kernel<<<dim3(64, 64, 4), 256, 0, stream>>>(Wq, Wk, Wv, Wo, Wt);
  ln_kernel<<<M, 256, 0, stream>>>(x, ln_g, ln_b, xn);
  gemm256<0><<<dim3(M / 256, 24), 512, 0, stream>>>(xn, 2048, Wt, bq, bk, bv, (void*)qkv);
  attn_kernel<<<M / 4, 256, 0, stream>>>(qkv);
  gemm256<1><<<dim3(M / 256, 8), 512, 0, stream>>>(qkv, 6144, Wt + (size_t)3 * 2048 * 2048,
                                                   bo, nullptr, nullptr, (void*)out);
}

// Round 7
// 622.988 us; speedup vs baseline: 1.1185x; 1.0020x over previous
//
#include <hip/hip_runtime.h>

typedef __bf16 bf16x8 __attribute__((ext_vector_type(8)));
typedef __bf16 bf16x4 __attribute__((ext_vector_type(4)));
typedef float  f32x4  __attribute__((ext_vector_type(4)));

#define GLOAD_LDS16(g, l) \
  __builtin_amdgcn_global_load_lds((const __attribute__((address_space(1))) void*)(g), \
                                   (__attribute__((address_space(3))) void*)(l), 16, 0, 0)

// ---------------------------------------------------------------------------
// Weight transpose + fp32->bf16 convert: W[K=2048][N=2048] -> Wt[N][K]
// ---------------------------------------------------------------------------
__global__ __launch_bounds__(256) void wcvt_kernel(
    const float* __restrict__ W0, const float* __restrict__ W1,
    const float* __restrict__ W2, const float* __restrict__ W3,
    __bf16* __restrict__ WtBase)
{
  const float* W = (blockIdx.z == 0) ? W0 : (blockIdx.z == 1) ? W1 : (blockIdx.z == 2) ? W2 : W3;
  __bf16* dst = WtBase + (size_t)blockIdx.z * 2048 * 2048;
  __shared__ float tile[32][33];
  const int tx = threadIdx.x & 31, ty = threadIdx.x >> 5;  // 32 x 8
  const int gi = blockIdx.x * 32, gj = blockIdx.y * 32;
  #pragma unroll
  for (int r = 0; r < 32; r += 8)
    tile[ty + r][tx] = W[(size_t)(gi + ty + r) * 2048 + gj + tx];
  __syncthreads();
  #pragma unroll
  for (int r = 0; r < 32; r += 8)
    dst[(size_t)(gj + ty + r) * 2048 + gi + tx] = (__bf16)tile[tx][ty + r];
}

// ---------------------------------------------------------------------------
// LayerNorm: x[M][2048] f32 -> xn[M][2048] bf16   (one block per token)
// ---------------------------------------------------------------------------
__global__ __launch_bounds__(256) void ln_kernel(
    const float* __restrict__ x, const float* __restrict__ gw,
    const float* __restrict__ bw, __bf16* __restrict__ xn)
{
  __shared__ float red[8];
  const size_t base = (size_t)blockIdx.x * 2048;
  const int t = threadIdx.x;
  float4 v0 = *(const float4*)(x + base + t * 4);
  float4 v1 = *(const float4*)(x + base + 1024 + t * 4);
  float sm = v0.x + v0.y + v0.z + v0.w + v1.x + v1.y + v1.z + v1.w;
  float sq = v0.x*v0.x + v0.y*v0.y + v0.z*v0.z + v0.w*v0.w
           + v1.x*v1.x + v1.y*v1.y + v1.z*v1.z + v1.w*v1.w;
  #pragma unroll
  for (int off = 32; off; off >>= 1) {
    sm += __shfl_down(sm, off);
    sq += __shfl_down(sq, off);
  }
  if ((t & 63) == 0) { red[t >> 6] = sm; red[4 + (t >> 6)] = sq; }
  __syncthreads();
  const float fs = red[0] + red[1] + red[2] + red[3];
  const float fq = red[4] + red[5] + red[6] + red[7];
  const float mu = fs * (1.f / 2048.f);
  const float var = fq * (1.f / 2048.f) - mu * mu;
  const float rs = rsqrtf(var + 1e-5f);
  float4 g0 = *(const float4*)(gw + t * 4);
  float4 g1 = *(const float4*)(gw + 1024 + t * 4);
  float4 b0 = *(const float4*)(bw + t * 4);
  float4 b1 = *(const float4*)(bw + 1024 + t * 4);
  bf16x4 o0, o1;
  o0[0] = (__bf16)((v0.x - mu) * rs * g0.x + b0.x);
  o0[1] = (__bf16)((v0.y - mu) * rs * g0.y + b0.y);
  o0[2] = (__bf16)((v0.z - mu) * rs * g0.z + b0.z);
  o0[3] = (__bf16)((v0.w - mu) * rs * g0.w + b0.w);
  o1[0] = (__bf16)((v1.x - mu) * rs * g1.x + b1.x);
  o1[1] = (__bf16)((v1.y - mu) * rs * g1.y + b1.y);
  o1[2] = (__bf16)((v1.z - mu) * rs * g1.z + b1.z);
  o1[3] = (__bf16)((v1.w - mu) * rs * g1.w + b1.w);
  *(bf16x4*)(xn + base + t * 4) = o0;
  *(bf16x4*)(xn + base + 1024 + t * 4) = o1;
}

// ---------------------------------------------------------------------------
// 256x256 GEMM, 8 waves (2M x 4N), BK=64, 4 phases per K-tile (m201-style
// fine interleave). LDS 128 KB = 2 dbuf x {A-half0,A-half1,B-half0,B-half1}
// of 16 KB each. Swizzle: within a half, row la (128B), phys_seg =
// log_seg ^ (la&7) (measured conflict-free).
// Phase = { ds_read frag-set; stage one half (2 gload_lds); barrier;
//           lgkmcnt(0); setprio1; 16 MFMA; setprio0; barrier }.
// vmcnt(6) ONCE per K-tile at phase 0 (covers all 4 phases: A0/B0/B1 of kt
// are older than A1(kt), the 6-deep guarantee; cross-wave via barriers);
// vmcnt(0) only at the last tile. No sched_barrier (m141: pinning hurts).
// Phase order (mh,nh): (0,0),(0,1),(1,1),(1,0) — B frags register-cached.
// Stage slots: phi0: A1(kt+1); phi1: A0(kt+2); phi2: B0(kt+2); phi3: B1(kt+2).
// MODE 0: QKV fused (blockIdx.y: which=y>>3, n0=(y&7)*256; bf16 out to qkv)
// MODE 1: O projection (fp32 out + bias to d_out)
// ---------------------------------------------------------------------------
template <int MODE>
__global__ __launch_bounds__(512, 2) void gemm256(
    const __bf16* __restrict__ A, int lda,
    const __bf16* __restrict__ WtBase,
    const float* __restrict__ b0, const float* __restrict__ b1,
    const float* __restrict__ b2, void* __restrict__ outp)
{
  __shared__ __attribute__((aligned(16))) char smem[131072];
  const int tid = threadIdx.x, lane = tid & 63, wid = tid >> 6;
  const int wm = wid >> 2, wn = wid & 3;
  const int m0 = blockIdx.x * 256;
  int which, n0;
  const __bf16* Bt;
  const float* bias;
  if (MODE == 0) {
    which = blockIdx.y >> 3;
    n0 = (blockIdx.y & 7) * 256;
    Bt = WtBase + (size_t)which * 2048 * 2048 + (size_t)n0 * 2048;
    bias = (which == 0) ? b0 : (which == 1) ? b1 : b2;
  } else {
    which = 0;
    n0 = blockIdx.y * 256;
    Bt = WtBase + (size_t)n0 * 2048;
    bias = b0;
  }

  // ---- staging: thread covers chunk ci0=tid (local row lr0=tid>>3) and
  //      ci1=tid+512 (local row lr0+64) of each 16KB half. Pre-swizzled
  //      global source: log_seg = (tid&7) ^ (lr0&7) (same for both chunks).
  const int lr0 = tid >> 3;
  const int sg  = (tid & 7) ^ (lr0 & 7);
  const __bf16* Ag0 = A + (size_t)(m0 + lr0) * lda + sg * 8;         // h=0,c0
  const __bf16* Ag1 = A + (size_t)(m0 + 64 + lr0) * lda + sg * 8;    // h=1,c0
  const __bf16* Bg0 = Bt + (size_t)((lr0 >> 5) * 64 + (lr0 & 31)) * 2048 + sg * 8;
  const __bf16* Bg1 = Bt + (size_t)((lr0 >> 5) * 64 + 32 + (lr0 & 31)) * 2048 + sg * 8;
  const int ldst = __builtin_amdgcn_readfirstlane(wid * 1024);

#define STAGE_A(H, DBB, KT)                                                        \
  do {                                                                             \
    GLOAD_LDS16(Ag##H + (KT) * 64, smem + (DBB) + (H) * 16384 + ldst);             \
    GLOAD_LDS16(Ag##H + (size_t)128 * lda + (KT) * 64,                             \
                smem + (DBB) + (H) * 16384 + 8192 + ldst);                         \
  } while (0)
#define STAGE_B(H, DBB, KT)                                                        \
  do {                                                                             \
    GLOAD_LDS16(Bg##H + (KT) * 64, smem + (DBB) + 32768 + (H) * 16384 + ldst);     \
    GLOAD_LDS16(Bg##H + 262144 + (KT) * 64,                                        \
                smem + (DBB) + 32768 + (H) * 16384 + 8192 + ldst);                 \
  } while (0)

  // ---- fragment read offsets within a half (local rows; swizzle XOR) ----
  const int fr = lane & 15, sl = lane >> 4, x7 = fr & 7;
  const int aoff0 = (wm * 64 + fr) * 128 + ((sl) ^ x7) * 16;
  const int aoff1 = (wm * 64 + fr) * 128 + ((4 + sl) ^ x7) * 16;
  const int boff0 = (wn * 32 + fr) * 128 + ((sl) ^ x7) * 16;
  const int boff1 = (wn * 32 + fr) * 128 + ((4 + sl) ^ x7) * 16;

  bf16x8 afr[4][2], bfr0[2][2], bfr1[2][2];
  f32x4 acc[8][4];
  #pragma unroll
  for (int i = 0; i < 8; i++)
    #pragma unroll
    for (int j = 0; j < 4; j++) acc[i][j] = (f32x4){0.f, 0.f, 0.f, 0.f};

#define READ_A(MH, DB)                                                             \
  _Pragma("unroll") for (int mi = 0; mi < 4; mi++)                                 \
  _Pragma("unroll") for (int kk = 0; kk < 2; kk++)                                 \
    afr[mi][kk] = *(const bf16x8*)(smem + (DB) + (MH) * 16384 +                    \
                                   (kk ? aoff1 : aoff0) + mi * 2048);
#define READ_B(NH, DB, DEST)                                                       \
  _Pragma("unroll") for (int ni = 0; ni < 2; ni++)                                 \
  _Pragma("unroll") for (int kk = 0; kk < 2; kk++)                                 \
    DEST[ni][kk] = *(const bf16x8*)(smem + (DB) + 32768 + (NH) * 16384 +           \
                                    (kk ? boff1 : boff0) + ni * 2048);
#define MFMA16(MH, NH, BSET)                                                       \
  _Pragma("unroll") for (int kk = 0; kk < 2; kk++)                                 \
  _Pragma("unroll") for (int mi = 0; mi < 4; mi++)                                 \
  _Pragma("unroll") for (int ni = 0; ni < 2; ni++)                                 \
    acc[(MH) * 4 + mi][(NH) * 2 + ni] = __builtin_amdgcn_mfma_f32_16x16x32_bf16(   \
        afr[mi][kk], BSET[ni][kk], acc[(MH) * 4 + mi][(NH) * 2 + ni], 0, 0, 0);
#define PHASE_TAIL(MH, NH, BSET)                                                   \
  __builtin_amdgcn_s_barrier();                                                    \
  asm volatile("s_waitcnt lgkmcnt(0)" ::: "memory");                               \
  __builtin_amdgcn_s_setprio(1);                                                   \
  MFMA16(MH, NH, BSET);                                                            \
  __builtin_amdgcn_s_setprio(0);                                                   \
  __builtin_amdgcn_s_barrier();

  // ---- prologue: kt0 {A0,B0,A1,B1} + kt1 {A0,B0,B1}; full drain once ----
  STAGE_A(0, 0, 0);
  STAGE_B(0, 0, 0);
  STAGE_A(1, 0, 0);
  STAGE_B(1, 0, 0);
  STAGE_A(0, 65536, 1);
  STAGE_B(0, 65536, 1);
  STAGE_B(1, 65536, 1);
  __syncthreads();

  const int NT = 32;  // 2048 / 64
  for (int kt = 0; kt < NT; kt++) {
    const int db  = (kt & 1) << 16;
    const int dbn = db ^ 65536;
    // ---- phase 0: (mh0, nh0); single vmcnt for the whole K-tile ----
    if (kt == NT - 1) { asm volatile("s_waitcnt vmcnt(0)" ::: "memory"); }
    else              { asm volatile("s_waitcnt vmcnt(6)" ::: "memory"); }
    READ_A(0, db);
    READ_B(0, db, bfr0);
    if (kt + 1 < NT) STAGE_A(1, dbn, kt + 1);
    PHASE_TAIL(0, 0, bfr0);
    // ---- phase 1: (mh0, nh1) ----
    READ_B(1, db, bfr1);
    if (kt + 2 < NT) STAGE_A(0, db, kt + 2);
    PHASE_TAIL(0, 1, bfr1);
    // ---- phase 2: (mh1, nh1) ----
    READ_A(1, db);
    if (kt + 2 < NT) STAGE_B(0, db, kt + 2);
    PHASE_TAIL(1, 1, bfr1);
    // ---- phase 3: (mh1, nh0) — no ds_reads (A,B frags cached) ----
    if (kt + 2 < NT) STAGE_B(1, db, kt + 2);
    PHASE_TAIL(1, 0, bfr0);
  }
#undef STAGE_A
#undef STAGE_B
#undef READ_A
#undef READ_B
#undef MFMA16
#undef PHASE_TAIL

  // epilogue: C/D layout col=lane&15, row=(lane>>4)*4+j  [m89-verified]
  const int colf = lane & 15, rowf = (lane >> 4) * 4;
  #pragma unroll
  for (int mi = 0; mi < 8; mi++) {
    const int rw = m0 + wm * 128 + mi * 16 + rowf;
    #pragma unroll
    for (int ni = 0; ni < 4; ni++) {
      const int cc = n0 + wn * 64 + ni * 16 + colf;
      const float bi = bias[cc];
      if (MODE == 0) {
        __bf16* qkv = (__bf16*)outp;
        #pragma unroll
        for (int j = 0; j < 4; j++)
          qkv[(size_t)(rw + j) * 6144 + (size_t)which * 2048 + cc] =
              (__bf16)(acc[mi][ni][j] + bi);
      } else {
        float* out = (float*)outp;
        #pragma unroll
        for (int j = 0; j < 4; j++)
          out[(size_t)(rw + j) * 2048 + cc] = acc[mi][ni][j] + bi;
      }
    }
  }
}

// ---------------------------------------------------------------------------
// Per-token attention: scores[16][16] = q@k^T/sqrt(2048), softmax rows,
// ctx[16][128] = P@v. One wave per token, 4 tokens/block. ctx overwrites the
// q-slot of qkv in place (safe: wave reads its token fully into LDS first).
// ---------------------------------------------------------------------------
__global__ __launch_bounds__(256) void attn_kernel(__bf16* __restrict__ qkv)
{
  __shared__ __bf16 att[4 * 6144];   // 48 KB
  __shared__ float Psh[4 * 256];     // 4 KB
  const int tid = threadIdx.x, lane = tid & 63, w = tid >> 6;
  const size_t token = (size_t)blockIdx.x * 4 + w;
  const __bf16* src = qkv + token * 6144;
  char* ldsb = (char*)att;
  const int lbase = __builtin_amdgcn_readfirstlane(w * 12288);
  #pragma unroll
  for (int r = 0; r < 12; r++)
    GLOAD_LDS16(src + r * 512 + lane * 8, ldsb + lbase + r * 1024);
  __syncthreads();

  const __bf16* my = att + w * 6144;
  // QK^T: lane handles h = lane>>2, g in {gq*4 .. gq*4+3}
  const int h = lane >> 2, gq = lane & 3;
  const __bf16* qrow = my + h * 128;
  float s[4] = {0.f, 0.f, 0.f, 0.f};
  for (int d = 0; d < 128; d += 8) {
    bf16x8 qv = *(const bf16x8*)(qrow + d);
    float qf[8];
    #pragma unroll
    for (int j = 0; j < 8; j++) qf[j] = (float)qv[j];
    #pragma unroll
    for (int i = 0; i < 4; i++) {
      bf16x8 kv = *(const bf16x8*)(my + 2048 + (gq * 4 + i) * 128 + d);
      #pragma unroll
      for (int j = 0; j < 8; j++) s[i] += qf[j] * (float)kv[j];
    }
  }
  const float scale = 0.022097086912079612f;  // 1/sqrt(2048)
  #pragma unroll
  for (int i = 0; i < 4; i++) s[i] *= scale;
  float mx = fmaxf(fmaxf(s[0], s[1]), fmaxf(s[2], s[3]));
  mx = fmaxf(mx, __shfl_xor(mx, 1));
  mx = fmaxf(mx, __shfl_xor(mx, 2));
  float p[4], sum = 0.f;
  #pragma unroll
  for (int i = 0; i < 4; i++) { p[i] = __expf(s[i] - mx); sum += p[i]; }
  sum += __shfl_xor(sum, 1);
  sum += __shfl_xor(sum, 2);
  const float inv = 1.f / sum;
  #pragma unroll
  for (int i = 0; i < 4; i++) Psh[w * 256 + h * 16 + gq * 4 + i] = p[i] * inv;
  __syncthreads();

  // PV: lane computes ctx[h2][db..db+31]
  const int h2 = lane >> 2, db = (lane & 3) * 32;
  const __bf16* vb = my + 4096;
  float acc[32];
  #pragma unroll
  for (int i = 0; i < 32; i++) acc[i] = 0.f;
  for (int g = 0; g < 16; g++) {
    const float pv = Psh[w * 256 + h2 * 16 + g];
    #pragma unroll
    for (int c = 0; c < 4; c++) {
      bf16x8 vv = *(const bf16x8*)(vb + g * 128 + db + c * 8);
      #pragma unroll
      for (int j = 0; j < 8; j++) acc[c * 8 + j] += pv * (float)vv[j];
    }
  }
  __bf16* dst = qkv + token * 6144 + h2 * 128 + db;
  #pragma unroll
  for (int c = 0; c < 4; c++) {
    bf16x8 ov;
    #pragma unroll
    for (int j = 0; j < 8; j++) ov[j] = (__bf16)acc[c * 8 + j];
    *(bf16x8*)(dst + c * 8) = ov;
  }
}

// ---------------------------------------------------------------------------
extern "C" void kernel_launch(void* const* d_in, const int* in_sizes, int n_in,
                              void* d_out, int out_size, void* d_ws, size_t ws_size,
                              hipStream_t stream)
{
  const float* x    = (const float*)d_in[0];
  const float* ln_g = (const float*)d_in[1];
  const float* ln_b = (const float*)d_in[2];
  const float* Wq   = (const float*)d_in[3];
  const float* bq   = (const float*)d_in[4];
  const float* Wk   = (const float*)d_in[5];
  const float* bk   = (const float*)d_in[6];
  const float* Wv   = (const float*)d_in[7];
  const float* bv   = (const float*)d_in[8];
  const float* Wo   = (const float*)d_in[9];
  const float* bo   = (const float*)d_in[10];
  float* out = (float*)d_out;
  const int M = in_sizes[0] / 2048;  // 16384

  // Workspace (224 MB): Wt 32 MB | qkv 192 MB. xn (64 MB bf16) lives in d_out
  // (128 MB fp32): consumed by QKV GEMM; d_out only written by final O-GEMM.
  char* ws = (char*)d_ws;
  __bf16* Wt  = (__bf16*)ws;
  __bf16* qkv = (__bf16*)(ws + 33554432);
  __bf16* xn  = (__bf16*)d_out;

  wcvt_kernel<<<dim3(64, 64, 4), 256, 0, stream>>>(Wq, Wk, Wv, Wo, Wt);
  ln_kernel<<<M, 256, 0, stream>>>(x, ln_g, ln_b, xn);
  gemm256<0><<<dim3(M / 256, 24), 512, 0, stream>>>(xn, 2048, Wt, bq, bk, bv, (void*)qkv);
  attn_kernel<<<M / 4, 256, 0, stream>>>(qkv);
  gemm256<1><<<dim3(M / 256, 8), 512, 0, stream>>>(qkv, 6144, Wt + (size_t)3 * 2048 * 2048,
                                                   bo, nullptr, nullptr, (void*)out);
}

// Round 8
// 610.316 us; speedup vs baseline: 1.1417x; 1.0208x over previous
//
#include <hip/hip_runtime.h>

typedef __bf16 bf16x8 __attribute__((ext_vector_type(8)));
typedef __bf16 bf16x4 __attribute__((ext_vector_type(4)));
typedef float  f32x4  __attribute__((ext_vector_type(4)));

#define GLOAD_LDS16(g, l) \
  __builtin_amdgcn_global_load_lds((const __attribute__((address_space(1))) void*)(g), \
                                   (__attribute__((address_space(3))) void*)(l), 16, 0, 0)

// ---------------------------------------------------------------------------
// Weight transpose + fp32->bf16 convert: W[K=2048][N=2048] -> Wt[N][K]
// ---------------------------------------------------------------------------
__global__ __launch_bounds__(256) void wcvt_kernel(
    const float* __restrict__ W0, const float* __restrict__ W1,
    const float* __restrict__ W2, const float* __restrict__ W3,
    __bf16* __restrict__ WtBase)
{
  const float* W = (blockIdx.z == 0) ? W0 : (blockIdx.z == 1) ? W1 : (blockIdx.z == 2) ? W2 : W3;
  __bf16* dst = WtBase + (size_t)blockIdx.z * 2048 * 2048;
  __shared__ float tile[32][33];
  const int tx = threadIdx.x & 31, ty = threadIdx.x >> 5;  // 32 x 8
  const int gi = blockIdx.x * 32, gj = blockIdx.y * 32;
  #pragma unroll
  for (int r = 0; r < 32; r += 8)
    tile[ty + r][tx] = W[(size_t)(gi + ty + r) * 2048 + gj + tx];
  __syncthreads();
  #pragma unroll
  for (int r = 0; r < 32; r += 8)
    dst[(size_t)(gj + ty + r) * 2048 + gi + tx] = (__bf16)tile[tx][ty + r];
}

// ---------------------------------------------------------------------------
// LayerNorm: x[M][2048] f32 -> xn[M][2048] bf16   (one block per token)
// ---------------------------------------------------------------------------
__global__ __launch_bounds__(256) void ln_kernel(
    const float* __restrict__ x, const float* __restrict__ gw,
    const float* __restrict__ bw, __bf16* __restrict__ xn)
{
  __shared__ float red[8];
  const size_t base = (size_t)blockIdx.x * 2048;
  const int t = threadIdx.x;
  float4 v0 = *(const float4*)(x + base + t * 4);
  float4 v1 = *(const float4*)(x + base + 1024 + t * 4);
  float sm = v0.x + v0.y + v0.z + v0.w + v1.x + v1.y + v1.z + v1.w;
  float sq = v0.x*v0.x + v0.y*v0.y + v0.z*v0.z + v0.w*v0.w
           + v1.x*v1.x + v1.y*v1.y + v1.z*v1.z + v1.w*v1.w;
  #pragma unroll
  for (int off = 32; off; off >>= 1) {
    sm += __shfl_down(sm, off);
    sq += __shfl_down(sq, off);
  }
  if ((t & 63) == 0) { red[t >> 6] = sm; red[4 + (t >> 6)] = sq; }
  __syncthreads();
  const float fs = red[0] + red[1] + red[2] + red[3];
  const float fq = red[4] + red[5] + red[6] + red[7];
  const float mu = fs * (1.f / 2048.f);
  const float var = fq * (1.f / 2048.f) - mu * mu;
  const float rs = rsqrtf(var + 1e-5f);
  float4 g0 = *(const float4*)(gw + t * 4);
  float4 g1 = *(const float4*)(gw + 1024 + t * 4);
  float4 b0 = *(const float4*)(bw + t * 4);
  float4 b1 = *(const float4*)(bw + 1024 + t * 4);
  bf16x4 o0, o1;
  o0[0] = (__bf16)((v0.x - mu) * rs * g0.x + b0.x);
  o0[1] = (__bf16)((v0.y - mu) * rs * g0.y + b0.y);
  o0[2] = (__bf16)((v0.z - mu) * rs * g0.z + b0.z);
  o0[3] = (__bf16)((v0.w - mu) * rs * g0.w + b0.w);
  o1[0] = (__bf16)((v1.x - mu) * rs * g1.x + b1.x);
  o1[1] = (__bf16)((v1.y - mu) * rs * g1.y + b1.y);
  o1[2] = (__bf16)((v1.z - mu) * rs * g1.z + b1.z);
  o1[3] = (__bf16)((v1.w - mu) * rs * g1.w + b1.w);
  *(bf16x4*)(xn + base + t * 4) = o0;
  *(bf16x4*)(xn + base + 1024 + t * 4) = o1;
}

// ---------------------------------------------------------------------------
// 256x256 GEMM, 8 waves (2M x 4N), BK=64, 4 phases/K-tile with REGISTER
// FRAGMENT PREFETCH: each phase's ds_reads load the NEXT phase's fragments
// and issue inside the MFMA window (overlap LDS reads with matrix math).
// Phase = { stage slot p; vmcnt(10); bar; lgkmcnt(0); setprio1;
//           [prefetch ds_reads ∥ 16 MFMA]; setprio0; bar }.
// FIFO proof: prefetch at phase p targets stage slot <= p-5; vmcnt(10) after
// issuing slot p forces slots <= p-5 (5 slots x 2 loads in flight); cross-wave
// safe since every wave's vmcnt precedes the opening barrier.
// Slots: P0: A1(kt+1)->dbn | P1: A0(kt+2)->db | P2: B0(kt+2)->db (no vmcnt,
// no reads) | P3: B1(kt+2)->db. Prefetch: P0 reads B1(kt); P1 reads A1(kt);
// P3 reads A0(kt+1)+B0(kt+1) from dbn. B0 frags kt-parity duplicated
// (bfr0e/bfr0o) -> kt-loop unrolled x2, static parity. Main loop kt=0..29
// guard-free; tail kt=30,31 peeled (vmcnt(0), read-then-MFMA, no barriers).
// LDS swizzle unchanged (T2, conflict-free). MODE as before.
// ---------------------------------------------------------------------------
template <int MODE>
__global__ __launch_bounds__(512, 2) void gemm256(
    const __bf16* __restrict__ A, int lda,
    const __bf16* __restrict__ WtBase,
    const float* __restrict__ b0, const float* __restrict__ b1,
    const float* __restrict__ b2, void* __restrict__ outp)
{
  __shared__ __attribute__((aligned(16))) char smem[131072];
  const int tid = threadIdx.x, lane = tid & 63, wid = tid >> 6;
  const int wm = wid >> 2, wn = wid & 3;
  const int m0 = blockIdx.x * 256;
  int which, n0;
  const __bf16* Bt;
  const float* bias;
  if (MODE == 0) {
    which = blockIdx.y >> 3;
    n0 = (blockIdx.y & 7) * 256;
    Bt = WtBase + (size_t)which * 2048 * 2048 + (size_t)n0 * 2048;
    bias = (which == 0) ? b0 : (which == 1) ? b1 : b2;
  } else {
    which = 0;
    n0 = blockIdx.y * 256;
    Bt = WtBase + (size_t)n0 * 2048;
    bias = b0;
  }

  // ---- staging (pre-swizzled global source), as r6/r7 ----
  const int lr0 = tid >> 3;
  const int sg  = (tid & 7) ^ (lr0 & 7);
  const __bf16* Ag0 = A + (size_t)(m0 + lr0) * lda + sg * 8;
  const __bf16* Ag1 = A + (size_t)(m0 + 64 + lr0) * lda + sg * 8;
  const __bf16* Bg0 = Bt + (size_t)((lr0 >> 5) * 64 + (lr0 & 31)) * 2048 + sg * 8;
  const __bf16* Bg1 = Bt + (size_t)((lr0 >> 5) * 64 + 32 + (lr0 & 31)) * 2048 + sg * 8;
  const int ldst = __builtin_amdgcn_readfirstlane(wid * 1024);

#define STAGE_A(H, DBB, KT)                                                        \
  do {                                                                             \
    GLOAD_LDS16(Ag##H + (KT) * 64, smem + (DBB) + (H) * 16384 + ldst);             \
    GLOAD_LDS16(Ag##H + (size_t)128 * lda + (KT) * 64,                             \
                smem + (DBB) + (H) * 16384 + 8192 + ldst);                         \
  } while (0)
#define STAGE_B(H, DBB, KT)                                                        \
  do {                                                                             \
    GLOAD_LDS16(Bg##H + (KT) * 64, smem + (DBB) + 32768 + (H) * 16384 + ldst);     \
    GLOAD_LDS16(Bg##H + 262144 + (KT) * 64,                                        \
                smem + (DBB) + 32768 + (H) * 16384 + 8192 + ldst);                 \
  } while (0)

  // ---- fragment read offsets within a half (swizzle XOR) ----
  const int fr = lane & 15, sl = lane >> 4, x7 = fr & 7;
  const int aoff0 = (wm * 64 + fr) * 128 + ((sl) ^ x7) * 16;
  const int aoff1 = (wm * 64 + fr) * 128 + ((4 + sl) ^ x7) * 16;
  const int boff0 = (wn * 32 + fr) * 128 + ((sl) ^ x7) * 16;
  const int boff1 = (wn * 32 + fr) * 128 + ((4 + sl) ^ x7) * 16;

  bf16x8 afrA[4][2], afrB[4][2], bfr1[2][2], bfr0e[2][2], bfr0o[2][2];
  f32x4 acc[8][4];
  #pragma unroll
  for (int i = 0; i < 8; i++)
    #pragma unroll
    for (int j = 0; j < 4; j++) acc[i][j] = (f32x4){0.f, 0.f, 0.f, 0.f};

#define READ_A_INTO(DEST, MH, DB)                                                  \
  _Pragma("unroll") for (int mi = 0; mi < 4; mi++)                                 \
  _Pragma("unroll") for (int kk = 0; kk < 2; kk++)                                 \
    DEST[mi][kk] = *(const bf16x8*)(smem + (DB) + (MH) * 16384 +                   \
                                    (kk ? aoff1 : aoff0) + mi * 2048);
#define READ_B_INTO(DEST, NH, DB)                                                  \
  _Pragma("unroll") for (int ni = 0; ni < 2; ni++)                                 \
  _Pragma("unroll") for (int kk = 0; kk < 2; kk++)                                 \
    DEST[ni][kk] = *(const bf16x8*)(smem + (DB) + 32768 + (NH) * 16384 +           \
                                    (kk ? boff1 : boff0) + ni * 2048);
#define MFMA16(MH, NH, ASET, BSET)                                                 \
  _Pragma("unroll") for (int kk = 0; kk < 2; kk++)                                 \
  _Pragma("unroll") for (int mi = 0; mi < 4; mi++)                                 \
  _Pragma("unroll") for (int ni = 0; ni < 2; ni++)                                 \
    acc[(MH) * 4 + mi][(NH) * 2 + ni] = __builtin_amdgcn_mfma_f32_16x16x32_bf16(   \
        ASET[mi][kk], BSET[ni][kk], acc[(MH) * 4 + mi][(NH) * 2 + ni], 0, 0, 0);

#define VM10 asm volatile("s_waitcnt vmcnt(10)" ::: "memory")
#define LGKM0 asm volatile("s_waitcnt lgkmcnt(0)" ::: "memory")
#define BAR __builtin_amdgcn_s_barrier()
#define PRIO1 __builtin_amdgcn_s_setprio(1)
#define PRIO0 __builtin_amdgcn_s_setprio(0)

  // One K-tile, static parity. DB = this tile's buffer, DBN = other buffer.
  // B0CUR = B0 frag set for this kt, B0NXT = set for kt+1.
#define KTILE(KT, DB, DBN, B0CUR, B0NXT)                                           \
  /* P0 */                                                                         \
  STAGE_A(1, DBN, (KT) + 1);                                                       \
  VM10; BAR; LGKM0; PRIO1;                                                         \
  READ_B_INTO(bfr1, 1, DB);                                                        \
  MFMA16(0, 0, afrA, B0CUR);                                                       \
  PRIO0; BAR;                                                                      \
  /* P1 */                                                                         \
  STAGE_A(0, DB, (KT) + 2);                                                        \
  VM10; BAR; LGKM0; PRIO1;                                                         \
  READ_A_INTO(afrB, 1, DB);                                                        \
  MFMA16(0, 1, afrA, bfr1);                                                        \
  PRIO0; BAR;                                                                      \
  /* P2 (no vmcnt, no reads) */                                                    \
  STAGE_B(0, DB, (KT) + 2);                                                        \
  BAR; LGKM0; PRIO1;                                                               \
  MFMA16(1, 1, afrB, bfr1);                                                        \
  PRIO0; BAR;                                                                      \
  /* P3 */                                                                         \
  STAGE_B(1, DB, (KT) + 2);                                                        \
  VM10; BAR; LGKM0; PRIO1;                                                         \
  READ_A_INTO(afrA, 0, DBN);                                                       \
  READ_B_INTO(B0NXT, 0, DBN);                                                      \
  MFMA16(1, 0, afrB, B0CUR);                                                       \
  PRIO0; BAR;

  // ---- prologue: kt0 {A0,B0,A1,B1}->buf0 + kt1 {A0,B0,B1}->buf1; drain ----
  STAGE_A(0, 0, 0);
  STAGE_B(0, 0, 0);
  STAGE_A(1, 0, 0);
  STAGE_B(1, 0, 0);
  STAGE_A(0, 65536, 1);
  STAGE_B(0, 65536, 1);
  STAGE_B(1, 65536, 1);
  __syncthreads();
  READ_A_INTO(afrA, 0, 0);
  READ_B_INTO(bfr0e, 0, 0);

  // ---- main loop: kt = 0..29, guard-free, x2 unrolled for parity ----
  for (int kt = 0; kt < 30; kt += 2) {
    KTILE(kt, 0, 65536, bfr0e, bfr0o);
    KTILE((kt + 1), 65536, 0, bfr0o, bfr0e);
  }

  // ---- tail: stage A1(31); full drain; kt=30 (buf0), kt=31 (buf1) ----
  STAGE_A(1, 65536, 31);
  asm volatile("s_waitcnt vmcnt(0)" ::: "memory");
  __syncthreads();
#define TAILTILE(DB)                                                               \
  READ_A_INTO(afrA, 0, DB);                                                        \
  READ_B_INTO(bfr0e, 0, DB);                                                       \
  LGKM0;                                                                           \
  MFMA16(0, 0, afrA, bfr0e);                                                       \
  READ_B_INTO(bfr1, 1, DB);                                                        \
  LGKM0;                                                                           \
  MFMA16(0, 1, afrA, bfr1);                                                        \
  READ_A_INTO(afrB, 1, DB);                                                        \
  LGKM0;                                                                           \
  MFMA16(1, 1, afrB, bfr1);                                                        \
  MFMA16(1, 0, afrB, bfr0e);
  TAILTILE(0);
  TAILTILE(65536);
#undef TAILTILE
#undef KTILE
#undef STAGE_A
#undef STAGE_B
#undef READ_A_INTO
#undef READ_B_INTO
#undef MFMA16
#undef VM10
#undef LGKM0
#undef BAR
#undef PRIO1
#undef PRIO0

  // epilogue: C/D layout col=lane&15, row=(lane>>4)*4+j  [m89-verified]
  const int colf = lane & 15, rowf = (lane >> 4) * 4;
  #pragma unroll
  for (int mi = 0; mi < 8; mi++) {
    const int rw = m0 + wm * 128 + mi * 16 + rowf;
    #pragma unroll
    for (int ni = 0; ni < 4; ni++) {
      const int cc = n0 + wn * 64 + ni * 16 + colf;
      const float bi = bias[cc];
      if (MODE == 0) {
        __bf16* qkv = (__bf16*)outp;
        #pragma unroll
        for (int j = 0; j < 4; j++)
          qkv[(size_t)(rw + j) * 6144 + (size_t)which * 2048 + cc] =
              (__bf16)(acc[mi][ni][j] + bi);
      } else {
        float* out = (float*)outp;
        #pragma unroll
        for (int j = 0; j < 4; j++)
          out[(size_t)(rw + j) * 2048 + cc] = acc[mi][ni][j] + bi;
      }
    }
  }
}

// ---------------------------------------------------------------------------
// Per-token attention: scores[16][16] = q@k^T/sqrt(2048), softmax rows,
// ctx[16][128] = P@v. One wave per token, 4 tokens/block. ctx overwrites the
// q-slot of qkv in place (safe: wave reads its token fully into LDS first).
// ---------------------------------------------------------------------------
__global__ __launch_bounds__(256) void attn_kernel(__bf16* __restrict__ qkv)
{
  __shared__ __bf16 att[4 * 6144];   // 48 KB
  __shared__ float Psh[4 * 256];     // 4 KB
  const int tid = threadIdx.x, lane = tid & 63, w = tid >> 6;
  const size_t token = (size_t)blockIdx.x * 4 + w;
  const __bf16* src = qkv + token * 6144;
  char* ldsb = (char*)att;
  const int lbase = __builtin_amdgcn_readfirstlane(w * 12288);
  #pragma unroll
  for (int r = 0; r < 12; r++)
    GLOAD_LDS16(src + r * 512 + lane * 8, ldsb + lbase + r * 1024);
  __syncthreads();

  const __bf16* my = att + w * 6144;
  // QK^T: lane handles h = lane>>2, g in {gq*4 .. gq*4+3}
  const int h = lane >> 2, gq = lane & 3;
  const __bf16* qrow = my + h * 128;
  float s[4] = {0.f, 0.f, 0.f, 0.f};
  for (int d = 0; d < 128; d += 8) {
    bf16x8 qv = *(const bf16x8*)(qrow + d);
    float qf[8];
    #pragma unroll
    for (int j = 0; j < 8; j++) qf[j] = (float)qv[j];
    #pragma unroll
    for (int i = 0; i < 4; i++) {
      bf16x8 kv = *(const bf16x8*)(my + 2048 + (gq * 4 + i) * 128 + d);
      #pragma unroll
      for (int j = 0; j < 8; j++) s[i] += qf[j] * (float)kv[j];
    }
  }
  const float scale = 0.022097086912079612f;  // 1/sqrt(2048)
  #pragma unroll
  for (int i = 0; i < 4; i++) s[i] *= scale;
  float mx = fmaxf(fmaxf(s[0], s[1]), fmaxf(s[2], s[3]));
  mx = fmaxf(mx, __shfl_xor(mx, 1));
  mx = fmaxf(mx, __shfl_xor(mx, 2));
  float p[4], sum = 0.f;
  #pragma unroll
  for (int i = 0; i < 4; i++) { p[i] = __expf(s[i] - mx); sum += p[i]; }
  sum += __shfl_xor(sum, 1);
  sum += __shfl_xor(sum, 2);
  const float inv = 1.f / sum;
  #pragma unroll
  for (int i = 0; i < 4; i++) Psh[w * 256 + h * 16 + gq * 4 + i] = p[i] * inv;
  __syncthreads();

  // PV: lane computes ctx[h2][db..db+31]
  const int h2 = lane >> 2, db = (lane & 3) * 32;
  const __bf16* vb = my + 4096;
  float acc[32];
  #pragma unroll
  for (int i = 0; i < 32; i++) acc[i] = 0.f;
  for (int g = 0; g < 16; g++) {
    const float pv = Psh[w * 256 + h2 * 16 + g];
    #pragma unroll
    for (int c = 0; c < 4; c++) {
      bf16x8 vv = *(const bf16x8*)(vb + g * 128 + db + c * 8);
      #pragma unroll
      for (int j = 0; j < 8; j++) acc[c * 8 + j] += pv * (float)vv[j];
    }
  }
  __bf16* dst = qkv + token * 6144 + h2 * 128 + db;
  #pragma unroll
  for (int c = 0; c < 4; c++) {
    bf16x8 ov;
    #pragma unroll
    for (int j = 0; j < 8; j++) ov[j] = (__bf16)acc[c * 8 + j];
    *(bf16x8*)(dst + c * 8) = ov;
  }
}

// ---------------------------------------------------------------------------
extern "C" void kernel_launch(void* const* d_in, const int* in_sizes, int n_in,
                              void* d_out, int out_size, void* d_ws, size_t ws_size,
                              hipStream_t stream)
{
  const float* x    = (const float*)d_in[0];
  const float* ln_g = (const float*)d_in[1];
  const float* ln_b = (const float*)d_in[2];
  const float* Wq   = (const float*)d_in[3];
  const float* bq   = (const float*)d_in[4];
  const float* Wk   = (const float*)d_in[5];
  const float* bk   = (const float*)d_in[6];
  const float* Wv   = (const float*)d_in[7];
  const float* bv   = (const float*)d_in[8];
  const float* Wo   = (const float*)d_in[9];
  const float* bo   = (const float*)d_in[10];
  float* out = (float*)d_out;
  const int M = in_sizes[0] / 2048;  // 16384

  // Workspace (224 MB): Wt 32 MB | qkv 192 MB. xn (64 MB bf16) lives in d_out
  // (128 MB fp32): consumed by QKV GEMM; d_out only written by final O-GEMM.
  char* ws = (char*)d_ws;
  __bf16* Wt  = (__bf16*)ws;
  __bf16* qkv = (__bf16*)(ws + 33554432);
  __bf16* xn  = (__bf16*)d_out;

  wcvt_kernel<<<dim3(64, 64, 4), 256, 0, stream>>>(Wq, Wk, Wv, Wo, Wt);
  ln_kernel<<<M, 256, 0, stream>>>(x, ln_g, ln_b, xn);
  gemm256<0><<<dim3(M / 256, 24), 512, 0, stream>>>(xn, 2048, Wt, bq, bk, bv, (void*)qkv);
  attn_kernel<<<M / 4, 256, 0, stream>>>(qkv);
  gemm256<1><<<dim3(M / 256, 8), 512, 0, stream>>>(qkv, 6144, Wt + (size_t)3 * 2048 * 2048,
                                                   bo, nullptr, nullptr, (void*)out);
}